// Round 1
// baseline (590.347 us; speedup 1.0000x reference)
//
#include <hip/hip_runtime.h>

#define N_NODES 50000
#define N_EDGES 800000
#define CDIM 100
#define HDIM 200
#define ODIM 100

// ---------------- CSR build ----------------

__global__ void count_deg(const int* __restrict__ dst, int* __restrict__ deg) {
    int e = blockIdx.x * 256 + threadIdx.x;
    if (e < N_EDGES) atomicAdd(&deg[dst[e]], 1);
}

__global__ __launch_bounds__(1024) void scan_deg(const int* __restrict__ deg,
                                                 int* __restrict__ off,
                                                 int* __restrict__ cursor) {
    const int T = 1024;
    const int per = (N_NODES + T - 1) / T;  // 49
    int t = threadIdx.x;
    int start = t * per;
    int end = min(start + per, N_NODES);
    int sum = 0;
    for (int i = start; i < end; ++i) sum += deg[i];
    __shared__ int ls[T];
    ls[t] = sum;
    __syncthreads();
    for (int o = 1; o < T; o <<= 1) {
        int v = (t >= o) ? ls[t - o] : 0;
        __syncthreads();
        ls[t] += v;
        __syncthreads();
    }
    int run = (t == 0) ? 0 : ls[t - 1];  // exclusive base
    for (int i = start; i < end; ++i) {
        off[i] = run;
        cursor[i] = run;
        run += deg[i];
    }
    if (t == T - 1) off[N_NODES] = run;
}

__global__ void scatter_edges(const int* __restrict__ src, const int* __restrict__ dst,
                              int* __restrict__ cursor, int* __restrict__ ssrc) {
    int e = blockIdx.x * 256 + threadIdx.x;
    if (e < N_EDGES) {
        int p = atomicAdd(&cursor[dst[e]], 1);
        ssrc[p] = src[e];
    }
}

// ---------------- embedding gather (float4, rows are 400B = 16B-aligned) ----------------

__global__ void gather_emb(const float4* __restrict__ emb, const int* __restrict__ ids,
                           float4* __restrict__ h0) {
    int i = blockIdx.x * 256 + threadIdx.x;
    const int TOT = N_NODES * (CDIM / 4);  // 1.25M
    if (i < TOT) {
        int n = i / 25, q = i - n * 25;
        h0[i] = emb[(size_t)ids[n] * 25 + q];
    }
}

// ---------------- per-node CSR aggregation (dim 100), optional bias+relu ----------------

template <bool BIAS_RELU>
__global__ __launch_bounds__(128) void agg_nodes(const float* __restrict__ h,
                                                 const int* __restrict__ ssrc,
                                                 const int* __restrict__ off,
                                                 const float* __restrict__ bias,
                                                 float* __restrict__ out) {
    int n = blockIdx.x;
    int d = threadIdx.x;
    int s0 = off[n], s1 = off[n + 1];
    if (d < 100) {
        float acc = 0.f;
        for (int j = s0; j < s1; ++j) {
            acc += h[(size_t)ssrc[j] * 100 + d];
        }
        if (BIAS_RELU) {
            acc += bias[d];
            acc = fmaxf(acc, 0.f);
        }
        out[(size_t)n * 100 + d] = acc;
    }
}

// ---------------- fp32 GEMM: out[M,N] = A[M,K] @ W[K,N] (+bias, relu) ----------------
// BM=64 rows/block, 256 threads, thread = (ty: 16 row-groups of 4, tx: 16 col lanes).
// W staged in LDS in K-strips of KT=20; A tile staged once (padded +1 to dodge bank conflicts).

template <int K, int N, bool BIAS_RELU>
__global__ __launch_bounds__(256) void gemm_node(const float* __restrict__ A,
                                                 const float* __restrict__ W,
                                                 const float* __restrict__ bias,
                                                 float* __restrict__ out) {
    const int BM = 64, KT = 20, NJ = (N + 15) / 16;
    static_assert(K % KT == 0, "K must be divisible by KT");
    __shared__ float As[BM][K + 1];
    __shared__ float Ws[KT * N];
    int tid = threadIdx.x;
    int tx = tid & 15, ty = tid >> 4;
    int row0 = blockIdx.x * BM;

    // stage A tile (coalesced; guard tail rows)
    for (int idx = tid; idx < BM * K; idx += 256) {
        int r = idx / K, c = idx - r * K;
        int row = row0 + r;
        As[r][c] = (row < N_NODES) ? A[(size_t)row * K + c] : 0.f;
    }

    float acc[4][NJ];
#pragma unroll
    for (int i = 0; i < 4; i++)
#pragma unroll
        for (int j = 0; j < NJ; j++) acc[i][j] = 0.f;

    for (int kt = 0; kt < K; kt += KT) {
        __syncthreads();  // protect Ws from previous iter readers; first iter: As visible
        const float4* Wv = (const float4*)(W + kt * N);
        float4* Wsv = (float4*)Ws;
        for (int idx = tid; idx < KT * N / 4; idx += 256) Wsv[idx] = Wv[idx];
        __syncthreads();
#pragma unroll
        for (int k = 0; k < KT; ++k) {
            float a[4];
#pragma unroll
            for (int i = 0; i < 4; i++) a[i] = As[ty * 4 + i][kt + k];
#pragma unroll
            for (int j = 0; j < NJ; j++) {
                int c = tx + 16 * j;
                if (c >= N) c = N - 1;  // clamp; junk lanes never stored
                float w = Ws[k * N + c];
#pragma unroll
                for (int i = 0; i < 4; i++) acc[i][j] += a[i] * w;
            }
        }
    }

#pragma unroll
    for (int i = 0; i < 4; i++) {
        int row = row0 + ty * 4 + i;
        if (row < N_NODES) {
#pragma unroll
            for (int j = 0; j < NJ; j++) {
                int c = tx + 16 * j;
                if (c < N) {
                    float v = acc[i][j];
                    if (BIAS_RELU) {
                        v += bias[c];
                        v = fmaxf(v, 0.f);
                    }
                    out[(size_t)row * N + c] = v;
                }
            }
        }
    }
}

// ---------------- launch ----------------

extern "C" void kernel_launch(void* const* d_in, const int* in_sizes, int n_in,
                              void* d_out, int out_size, void* d_ws, size_t ws_size,
                              hipStream_t stream) {
    const float* emb = (const float*)d_in[0];
    const float* W1  = (const float*)d_in[1];
    const float* b1  = (const float*)d_in[2];
    const float* W2  = (const float*)d_in[3];
    const float* b2  = (const float*)d_in[4];
    const int* ids   = (const int*)d_in[5];
    const int* esrc  = (const int*)d_in[6];
    const int* edst  = (const int*)d_in[7];
    float* out = (float*)d_out;

    // workspace layout (~64 MB)
    float* h0g = (float*)d_ws;                         // 5M floats: h0, later g = h1@W2
    float* h1  = h0g + (size_t)N_NODES * CDIM;         // 10M floats
    int* deg    = (int*)(h1 + (size_t)N_NODES * HDIM);
    int* off    = deg + N_NODES;
    int* cursor = off + (N_NODES + 1);
    int* ssrc   = cursor + N_NODES;                    // 800K ints

    // CSR build (reused by both layers)
    hipMemsetAsync(deg, 0, N_NODES * sizeof(int), stream);
    count_deg<<<(N_EDGES + 255) / 256, 256, 0, stream>>>(edst, deg);
    scan_deg<<<1, 1024, 0, stream>>>(deg, off, cursor);
    scatter_edges<<<(N_EDGES + 255) / 256, 256, 0, stream>>>(esrc, edst, cursor, ssrc);

    // h0 = emb[ids]
    gather_emb<<<(N_NODES * 25 + 255) / 256, 256, 0, stream>>>((const float4*)emb, ids,
                                                               (float4*)h0g);
    // agg1 = segsum(h0[src]) -> d_out (dim 100)
    agg_nodes<false><<<N_NODES, 128, 0, stream>>>(h0g, ssrc, off, nullptr, out);
    // h1 = relu(agg1 @ W1 + b1)
    gemm_node<CDIM, HDIM, true><<<(N_NODES + 63) / 64, 256, 0, stream>>>(out, W1, b1, h1);
    // g = h1 @ W2   (defer bias+relu past the linear aggregation)
    gemm_node<HDIM, ODIM, false><<<(N_NODES + 63) / 64, 256, 0, stream>>>(h1, W2, nullptr, h0g);
    // out = relu(segsum(g[src]) + b2)
    agg_nodes<true><<<N_NODES, 128, 0, stream>>>(h0g, ssrc, off, b2, out);
}

// Round 2
// 462.851 us; speedup vs baseline: 1.2755x; 1.2755x over previous
//
#include <hip/hip_runtime.h>

#define N_NODES 50000
#define N_EDGES 800000
#define CDIM 100
#define HDIM 200
#define ODIM 100

// ---------------- CSR build ----------------

__global__ void count_deg(const int* __restrict__ dst, int* __restrict__ deg) {
    int e = blockIdx.x * 256 + threadIdx.x;
    if (e < N_EDGES) atomicAdd(&deg[dst[e]], 1);
}

__global__ __launch_bounds__(1024) void scan_deg(const int* __restrict__ deg,
                                                 int* __restrict__ off,
                                                 int* __restrict__ cursor) {
    const int T = 1024;
    const int per = (N_NODES + T - 1) / T;  // 49
    int t = threadIdx.x;
    int start = t * per;
    int end = min(start + per, N_NODES);
    int sum = 0;
    for (int i = start; i < end; ++i) sum += deg[i];
    __shared__ int ls[T];
    ls[t] = sum;
    __syncthreads();
    for (int o = 1; o < T; o <<= 1) {
        int v = (t >= o) ? ls[t - o] : 0;
        __syncthreads();
        ls[t] += v;
        __syncthreads();
    }
    int run = (t == 0) ? 0 : ls[t - 1];  // exclusive base
    for (int i = start; i < end; ++i) {
        off[i] = run;
        cursor[i] = run;
        run += deg[i];
    }
    if (t == T - 1) off[N_NODES] = run;
}

__global__ void scatter_edges(const int* __restrict__ src, const int* __restrict__ dst,
                              int* __restrict__ cursor, int* __restrict__ ssrc) {
    int e = blockIdx.x * 256 + threadIdx.x;
    if (e < N_EDGES) {
        int p = atomicAdd(&cursor[dst[e]], 1);
        ssrc[p] = src[e];
    }
}

// ---------------- embedding gather (float4, rows are 400B = 16B-aligned) ----------------

__global__ void gather_emb(const float4* __restrict__ emb, const int* __restrict__ ids,
                           float4* __restrict__ h0) {
    int i = blockIdx.x * 256 + threadIdx.x;
    const int TOT = N_NODES * (CDIM / 4);  // 1.25M
    if (i < TOT) {
        int n = i / 25, q = i - n * 25;
        h0[i] = emb[(size_t)ids[n] * 25 + q];
    }
}

// ---------------- CSR aggregation: 1 wave per node, 50 lanes x float2 ----------------

template <bool BIAS_RELU>
__global__ __launch_bounds__(256) void agg_nodes2(const float2* __restrict__ h2,
                                                  const int* __restrict__ ssrc,
                                                  const int* __restrict__ off,
                                                  const float* __restrict__ bias,
                                                  float2* __restrict__ out2) {
    int wave = threadIdx.x >> 6;
    int lane = threadIdx.x & 63;
    int n = blockIdx.x * 4 + wave;
    if (n >= N_NODES) return;
    int s0 = off[n], s1 = off[n + 1];
    if (lane >= 50) return;

    float2 a0 = {0.f, 0.f}, a1 = {0.f, 0.f};
    int j = s0;
    for (; j + 1 < s1; j += 2) {
        int r0 = ssrc[j];
        int r1 = ssrc[j + 1];
        float2 v0 = h2[(size_t)r0 * 50 + lane];
        float2 v1 = h2[(size_t)r1 * 50 + lane];
        a0.x += v0.x; a0.y += v0.y;
        a1.x += v1.x; a1.y += v1.y;
    }
    if (j < s1) {
        int r = ssrc[j];
        float2 v = h2[(size_t)r * 50 + lane];
        a0.x += v.x; a0.y += v.y;
    }
    float2 res = {a0.x + a1.x, a0.y + a1.y};
    if (BIAS_RELU) {
        res.x = fmaxf(res.x + bias[2 * lane], 0.f);
        res.y = fmaxf(res.y + bias[2 * lane + 1], 0.f);
    }
    out2[(size_t)n * 50 + lane] = res;
}

// ---------------- fp32 GEMM v2: out[M,N] = A[M,K] @ W[K,N] (+bias, relu) ----------------
// BM=64 rows/block, 256 threads = 16 tx (col quads) x 16 ty (4-row groups).
// Thread computes 4 rows x NQ float4 col-quads (cols 4*tx + 64*jj).
// W staged in LDS K-strips of KT=20, read as conflict-free float4 (stride 16B across lanes).
// A staged row-major with 16B-aligned padded stride; a-reads are 16-lane b32 broadcasts.

template <int K, int N, bool BIAS_RELU>
__global__ __launch_bounds__(256) void gemm2(const float* __restrict__ A,
                                             const float* __restrict__ W,
                                             const float* __restrict__ bias,
                                             float* __restrict__ out) {
    const int BM = 64, KT = 20;
    const int NQ = (N + 63) / 64;   // col quads per thread
    const int KP = K + 4;           // padded row stride (16B-aligned, breaks pow2 banks)
    static_assert(K % KT == 0, "K % KT");
    static_assert(N % 4 == 0, "N % 4");
    __shared__ float As[BM][KP];
    __shared__ float Ws[KT][N];
    int tid = threadIdx.x;
    int tx = tid & 15, ty = tid >> 4;
    int row0 = blockIdx.x * BM;

    // stage A tile (coalesced b32; guard tail rows)
    for (int idx = tid; idx < BM * K; idx += 256) {
        int r = idx / K, c = idx - r * K;
        int row = row0 + r;
        As[r][c] = (row < N_NODES) ? A[(size_t)row * K + c] : 0.f;
    }

    float4 acc[4][NQ];
#pragma unroll
    for (int i = 0; i < 4; i++)
#pragma unroll
        for (int jj = 0; jj < NQ; jj++) acc[i][jj] = make_float4(0.f, 0.f, 0.f, 0.f);

    for (int kt = 0; kt < K; kt += KT) {
        __syncthreads();  // Ws readers from prev strip done; first iter: As visible
        const float4* Wv = (const float4*)(W + (size_t)kt * N);
        float4* Wsv = (float4*)&Ws[0][0];
        for (int idx = tid; idx < KT * N / 4; idx += 256) Wsv[idx] = Wv[idx];
        __syncthreads();
#pragma unroll
        for (int k = 0; k < KT; ++k) {
            float a[4];
#pragma unroll
            for (int i = 0; i < 4; i++) a[i] = As[ty * 4 + i][kt + k];
#pragma unroll
            for (int jj = 0; jj < NQ; jj++) {
                int cb = 4 * tx + 64 * jj;
                if (cb > N - 4) cb = N - 4;  // clamp (junk never stored)
                float4 w = *(const float4*)&Ws[k][cb];
#pragma unroll
                for (int i = 0; i < 4; i++) {
                    acc[i][jj].x += a[i] * w.x;
                    acc[i][jj].y += a[i] * w.y;
                    acc[i][jj].z += a[i] * w.z;
                    acc[i][jj].w += a[i] * w.w;
                }
            }
        }
    }

#pragma unroll
    for (int i = 0; i < 4; i++) {
        int row = row0 + ty * 4 + i;
        if (row < N_NODES) {
#pragma unroll
            for (int jj = 0; jj < NQ; jj++) {
                int cb = 4 * tx + 64 * jj;  // raw (unclamped)
                if (cb <= N - 4) {
                    float4 v = acc[i][jj];
                    if (BIAS_RELU) {
                        v.x = fmaxf(v.x + bias[cb + 0], 0.f);
                        v.y = fmaxf(v.y + bias[cb + 1], 0.f);
                        v.z = fmaxf(v.z + bias[cb + 2], 0.f);
                        v.w = fmaxf(v.w + bias[cb + 3], 0.f);
                    }
                    *(float4*)&out[(size_t)row * N + cb] = v;
                }
            }
        }
    }
}

// ---------------- launch ----------------

extern "C" void kernel_launch(void* const* d_in, const int* in_sizes, int n_in,
                              void* d_out, int out_size, void* d_ws, size_t ws_size,
                              hipStream_t stream) {
    const float* emb = (const float*)d_in[0];
    const float* W1  = (const float*)d_in[1];
    const float* b1  = (const float*)d_in[2];
    const float* W2  = (const float*)d_in[3];
    const float* b2  = (const float*)d_in[4];
    const int* ids   = (const int*)d_in[5];
    const int* esrc  = (const int*)d_in[6];
    const int* edst  = (const int*)d_in[7];
    float* out = (float*)d_out;

    float* h0g = (float*)d_ws;                         // 5M floats: h0, later g = h1@W2
    float* h1  = h0g + (size_t)N_NODES * CDIM;         // 10M floats
    int* deg    = (int*)(h1 + (size_t)N_NODES * HDIM);
    int* off    = deg + N_NODES;
    int* cursor = off + (N_NODES + 1);
    int* ssrc   = cursor + N_NODES;                    // 800K ints

    // CSR build (reused by both layers)
    hipMemsetAsync(deg, 0, N_NODES * sizeof(int), stream);
    count_deg<<<(N_EDGES + 255) / 256, 256, 0, stream>>>(edst, deg);
    scan_deg<<<1, 1024, 0, stream>>>(deg, off, cursor);
    scatter_edges<<<(N_EDGES + 255) / 256, 256, 0, stream>>>(esrc, edst, cursor, ssrc);

    // h0 = emb[ids]
    gather_emb<<<(N_NODES * 25 + 255) / 256, 256, 0, stream>>>((const float4*)emb, ids,
                                                               (float4*)h0g);
    // agg1 = segsum(h0[src]) -> d_out (dim 100)
    agg_nodes2<false><<<N_NODES / 4, 256, 0, stream>>>((const float2*)h0g, ssrc, off,
                                                       nullptr, (float2*)out);
    // h1 = relu(agg1 @ W1 + b1)
    gemm2<CDIM, HDIM, true><<<(N_NODES + 63) / 64, 256, 0, stream>>>(out, W1, b1, h1);
    // g = h1 @ W2   (defer bias+relu past the linear aggregation)
    gemm2<HDIM, ODIM, false><<<(N_NODES + 63) / 64, 256, 0, stream>>>(h1, W2, nullptr, h0g);
    // out = relu(segsum(g[src]) + b2)
    agg_nodes2<true><<<N_NODES / 4, 256, 0, stream>>>((const float2*)h0g, ssrc, off,
                                                      b2, (float2*)out);
}

// Round 3
// 368.854 us; speedup vs baseline: 1.6005x; 1.2548x over previous
//
#include <hip/hip_runtime.h>

#define N_NODES 50000
#define N_EDGES 800000
#define CDIM 100
#define HDIM 200
#define ODIM 100

// ---------------- CSR build ----------------

__global__ void count_deg(const int* __restrict__ dst, int* __restrict__ deg) {
    int e = blockIdx.x * 256 + threadIdx.x;
    if (e < N_EDGES) atomicAdd(&deg[dst[e]], 1);
}

// single-block scan, int4-vectorized: off = exclusive prefix of deg, cursor = copy
__global__ __launch_bounds__(1024) void scan_deg(const int* __restrict__ deg,
                                                 int* __restrict__ off,
                                                 int* __restrict__ cursor) {
    const int T = 1024;
    const int PER = 52;  // 13 int4s; 962 threads cover 50000
    int t = threadIdx.x;
    int start = t * PER;
    const int4* deg4 = (const int4*)deg;

    // pass 1: per-thread sum
    int sum = 0;
    if (start + PER <= N_NODES) {
#pragma unroll
        for (int q = 0; q < PER / 4; ++q) {
            int4 v = deg4[start / 4 + q];
            sum += v.x + v.y + v.z + v.w;
        }
    } else {
        for (int i = start; i < N_NODES; ++i) sum += deg[i];
    }

    __shared__ int ls[T];
    ls[t] = sum;
    __syncthreads();
    for (int o = 1; o < T; o <<= 1) {
        int v = (t >= o) ? ls[t - o] : 0;
        __syncthreads();
        ls[t] += v;
        __syncthreads();
    }
    int run = (t == 0) ? 0 : ls[t - 1];  // exclusive base

    // pass 2: write offsets
    if (start + PER <= N_NODES) {
        int4* off4 = (int4*)off;
        int4* cur4 = (int4*)cursor;
#pragma unroll
        for (int q = 0; q < PER / 4; ++q) {
            int4 v = deg4[start / 4 + q];
            int4 o;
            o.x = run;
            o.y = o.x + v.x;
            o.z = o.y + v.y;
            o.w = o.z + v.z;
            run = o.w + v.w;
            off4[start / 4 + q] = o;
            cur4[start / 4 + q] = o;
        }
    } else if (start <= N_NODES) {
        for (int i = start; i < N_NODES; ++i) {
            off[i] = run;
            cursor[i] = run;
            run += deg[i];
        }
        off[N_NODES] = run;  // exactly one thread has start <= N < start+PER
    }
}

__global__ void scatter_edges(const int* __restrict__ src, const int* __restrict__ dst,
                              int* __restrict__ cursor, int* __restrict__ ssrc) {
    int e = blockIdx.x * 256 + threadIdx.x;
    if (e < N_EDGES) {
        int p = atomicAdd(&cursor[dst[e]], 1);
        ssrc[p] = src[e];
    }
}

// ---------------- embedding gather (float4, rows are 400B = 16B-aligned) ----------------

__global__ void gather_emb(const float4* __restrict__ emb, const int* __restrict__ ids,
                           float4* __restrict__ h0) {
    int i = blockIdx.x * 256 + threadIdx.x;
    const int TOT = N_NODES * (CDIM / 4);  // 1.25M
    if (i < TOT) {
        int n = i / 25, q = i - n * 25;
        h0[i] = emb[(size_t)ids[n] * 25 + q];
    }
}

// ---------------- CSR aggregation: 1 wave/node, 50 lanes x float2, 4-deep ILP ----------

template <bool BIAS_RELU>
__global__ __launch_bounds__(256) void agg_nodes4(const float2* __restrict__ h2,
                                                  const int* __restrict__ ssrc,
                                                  const int* __restrict__ off,
                                                  const float* __restrict__ bias,
                                                  float2* __restrict__ out2) {
    int wave = threadIdx.x >> 6;
    int lane = threadIdx.x & 63;
    int n = blockIdx.x * 4 + wave;
    if (n >= N_NODES) return;
    int s0 = off[n], s1 = off[n + 1];
    if (lane >= 50) return;

    float2 a0 = {0.f, 0.f}, a1 = {0.f, 0.f}, a2 = {0.f, 0.f}, a3 = {0.f, 0.f};
    int j = s0;
    for (; j + 3 < s1; j += 4) {
        int r0 = ssrc[j], r1 = ssrc[j + 1], r2 = ssrc[j + 2], r3 = ssrc[j + 3];
        float2 v0 = h2[(size_t)r0 * 50 + lane];
        float2 v1 = h2[(size_t)r1 * 50 + lane];
        float2 v2 = h2[(size_t)r2 * 50 + lane];
        float2 v3 = h2[(size_t)r3 * 50 + lane];
        a0.x += v0.x; a0.y += v0.y;
        a1.x += v1.x; a1.y += v1.y;
        a2.x += v2.x; a2.y += v2.y;
        a3.x += v3.x; a3.y += v3.y;
    }
    // tail (<=3), independent predicated loads — no serial chain
    {
        int rem = s1 - j;
        if (rem > 0) {
            float2 v = h2[(size_t)ssrc[j] * 50 + lane];
            a0.x += v.x; a0.y += v.y;
        }
        if (rem > 1) {
            float2 v = h2[(size_t)ssrc[j + 1] * 50 + lane];
            a1.x += v.x; a1.y += v.y;
        }
        if (rem > 2) {
            float2 v = h2[(size_t)ssrc[j + 2] * 50 + lane];
            a2.x += v.x; a2.y += v.y;
        }
    }
    float2 res = {(a0.x + a1.x) + (a2.x + a3.x), (a0.y + a1.y) + (a2.y + a3.y)};
    if (BIAS_RELU) {
        res.x = fmaxf(res.x + bias[2 * lane], 0.f);
        res.y = fmaxf(res.y + bias[2 * lane + 1], 0.f);
    }
    out2[(size_t)n * 50 + lane] = res;
}

// ---------------- fp32 GEMM v2: out[M,N] = A[M,K] @ W[K,N] (+bias, relu) ----------------

template <int K, int N, bool BIAS_RELU>
__global__ __launch_bounds__(256) void gemm2(const float* __restrict__ A,
                                             const float* __restrict__ W,
                                             const float* __restrict__ bias,
                                             float* __restrict__ out) {
    const int BM = 64, KT = 20;
    const int NQ = (N + 63) / 64;   // col quads per thread
    const int KP = K + 4;           // padded row stride (16B-aligned, breaks pow2 banks)
    static_assert(K % KT == 0, "K % KT");
    static_assert(N % 4 == 0, "N % 4");
    __shared__ float As[BM][KP];
    __shared__ float Ws[KT][N];
    int tid = threadIdx.x;
    int tx = tid & 15, ty = tid >> 4;
    int row0 = blockIdx.x * BM;

    // stage A tile (coalesced b32; guard tail rows; /K,%K are const-div -> mul/shift)
    for (int idx = tid; idx < BM * K; idx += 256) {
        int r = idx / K, c = idx - r * K;
        int row = row0 + r;
        As[r][c] = (row < N_NODES) ? A[(size_t)row * K + c] : 0.f;
    }

    float4 acc[4][NQ];
#pragma unroll
    for (int i = 0; i < 4; i++)
#pragma unroll
        for (int jj = 0; jj < NQ; jj++) acc[i][jj] = make_float4(0.f, 0.f, 0.f, 0.f);

    for (int kt = 0; kt < K; kt += KT) {
        __syncthreads();  // Ws readers from prev strip done; first iter: As visible
        const float4* Wv = (const float4*)(W + (size_t)kt * N);
        float4* Wsv = (float4*)&Ws[0][0];
        for (int idx = tid; idx < KT * N / 4; idx += 256) Wsv[idx] = Wv[idx];
        __syncthreads();
#pragma unroll
        for (int k = 0; k < KT; ++k) {
            float a[4];
#pragma unroll
            for (int i = 0; i < 4; i++) a[i] = As[ty * 4 + i][kt + k];
#pragma unroll
            for (int jj = 0; jj < NQ; jj++) {
                int cb = 4 * tx + 64 * jj;
                if (cb > N - 4) cb = N - 4;  // clamp (junk never stored)
                float4 w = *(const float4*)&Ws[k][cb];
#pragma unroll
                for (int i = 0; i < 4; i++) {
                    acc[i][jj].x += a[i] * w.x;
                    acc[i][jj].y += a[i] * w.y;
                    acc[i][jj].z += a[i] * w.z;
                    acc[i][jj].w += a[i] * w.w;
                }
            }
        }
    }

#pragma unroll
    for (int i = 0; i < 4; i++) {
        int row = row0 + ty * 4 + i;
        if (row < N_NODES) {
#pragma unroll
            for (int jj = 0; jj < NQ; jj++) {
                int cb = 4 * tx + 64 * jj;  // raw (unclamped)
                if (cb <= N - 4) {
                    float4 v = acc[i][jj];
                    if (BIAS_RELU) {
                        v.x = fmaxf(v.x + bias[cb + 0], 0.f);
                        v.y = fmaxf(v.y + bias[cb + 1], 0.f);
                        v.z = fmaxf(v.z + bias[cb + 2], 0.f);
                        v.w = fmaxf(v.w + bias[cb + 3], 0.f);
                    }
                    *(float4*)&out[(size_t)row * N + cb] = v;
                }
            }
        }
    }
}

// ---------------- launch ----------------

extern "C" void kernel_launch(void* const* d_in, const int* in_sizes, int n_in,
                              void* d_out, int out_size, void* d_ws, size_t ws_size,
                              hipStream_t stream) {
    const float* emb = (const float*)d_in[0];
    const float* W1  = (const float*)d_in[1];
    const float* b1  = (const float*)d_in[2];
    const float* W2  = (const float*)d_in[3];
    const float* b2  = (const float*)d_in[4];
    const int* ids   = (const int*)d_in[5];
    const int* esrc  = (const int*)d_in[6];
    const int* edst  = (const int*)d_in[7];
    float* out = (float*)d_out;

    float* h0g = (float*)d_ws;                         // 5M floats: h0, later g = h1@W2
    float* h1  = h0g + (size_t)N_NODES * CDIM;         // 10M floats
    int* deg    = (int*)(h1 + (size_t)N_NODES * HDIM);
    int* off    = deg + N_NODES;
    int* cursor = off + (N_NODES + 1);
    int* ssrc   = cursor + N_NODES;                    // 800K ints

    // CSR build (reused by both layers)
    hipMemsetAsync(deg, 0, N_NODES * sizeof(int), stream);
    count_deg<<<(N_EDGES + 255) / 256, 256, 0, stream>>>(edst, deg);
    scan_deg<<<1, 1024, 0, stream>>>(deg, off, cursor);
    scatter_edges<<<(N_EDGES + 255) / 256, 256, 0, stream>>>(esrc, edst, cursor, ssrc);

    // h0 = emb[ids]
    gather_emb<<<(N_NODES * 25 + 255) / 256, 256, 0, stream>>>((const float4*)emb, ids,
                                                               (float4*)h0g);
    // agg1 = segsum(h0[src]) -> d_out (dim 100)
    agg_nodes4<false><<<N_NODES / 4, 256, 0, stream>>>((const float2*)h0g, ssrc, off,
                                                       nullptr, (float2*)out);
    // h1 = relu(agg1 @ W1 + b1)
    gemm2<CDIM, HDIM, true><<<(N_NODES + 63) / 64, 256, 0, stream>>>(out, W1, b1, h1);
    // g = h1 @ W2   (defer bias+relu past the linear aggregation)
    gemm2<HDIM, ODIM, false><<<(N_NODES + 63) / 64, 256, 0, stream>>>(h1, W2, nullptr, h0g);
    // out = relu(segsum(g[src]) + b2)
    agg_nodes4<true><<<N_NODES / 4, 256, 0, stream>>>((const float2*)h0g, ssrc, off,
                                                      b2, (float2*)out);
}

// Round 4
// 283.129 us; speedup vs baseline: 2.0851x; 1.3028x over previous
//
#include <hip/hip_runtime.h>

#define N_NODES 50000
#define N_EDGES 800000
#define CDIM 100
#define HDIM 200
#define ODIM 100

typedef __bf16 bf16x8 __attribute__((ext_vector_type(8)));
typedef float f32x4 __attribute__((ext_vector_type(4)));
typedef unsigned short ushort_t;

__device__ __forceinline__ unsigned f2bf(float f) {
    unsigned u = __float_as_uint(f);
    u = (u + 0x7FFFu + ((u >> 16) & 1u)) >> 16;
    return u;  // low 16 bits valid
}
__device__ __forceinline__ float bflo(unsigned u) { return __uint_as_float(u << 16); }
__device__ __forceinline__ float bfhi(unsigned u) { return __uint_as_float(u & 0xFFFF0000u); }

// ---------------- CSR build ----------------

__global__ void count_deg(const int* __restrict__ dst, int* __restrict__ deg) {
    int e = blockIdx.x * 256 + threadIdx.x;
    if (e < N_EDGES) atomicAdd(&deg[dst[e]], 1);
}

__global__ __launch_bounds__(1024) void scan_deg(const int* __restrict__ deg,
                                                 int* __restrict__ off,
                                                 int* __restrict__ cursor) {
    const int T = 1024;
    const int PER = 52;  // 13 int4s; 962 threads cover 50000
    int t = threadIdx.x;
    int start = t * PER;
    const int4* deg4 = (const int4*)deg;

    int sum = 0;
    if (start + PER <= N_NODES) {
#pragma unroll
        for (int q = 0; q < PER / 4; ++q) {
            int4 v = deg4[start / 4 + q];
            sum += v.x + v.y + v.z + v.w;
        }
    } else {
        for (int i = start; i < N_NODES; ++i) sum += deg[i];
    }

    __shared__ int ls[T];
    ls[t] = sum;
    __syncthreads();
    for (int o = 1; o < T; o <<= 1) {
        int v = (t >= o) ? ls[t - o] : 0;
        __syncthreads();
        ls[t] += v;
        __syncthreads();
    }
    int run = (t == 0) ? 0 : ls[t - 1];

    if (start + PER <= N_NODES) {
        int4* off4 = (int4*)off;
        int4* cur4 = (int4*)cursor;
#pragma unroll
        for (int q = 0; q < PER / 4; ++q) {
            int4 v = deg4[start / 4 + q];
            int4 o;
            o.x = run;
            o.y = o.x + v.x;
            o.z = o.y + v.y;
            o.w = o.z + v.z;
            run = o.w + v.w;
            off4[start / 4 + q] = o;
            cur4[start / 4 + q] = o;
        }
    } else if (start <= N_NODES) {
        for (int i = start; i < N_NODES; ++i) {
            off[i] = run;
            cursor[i] = run;
            run += deg[i];
        }
        off[N_NODES] = run;
    }
}

__global__ void scatter_edges(const int* __restrict__ src, const int* __restrict__ dst,
                              int* __restrict__ cursor, int* __restrict__ ssrc) {
    int e = blockIdx.x * 256 + threadIdx.x;
    if (e < N_EDGES) {
        int p = atomicAdd(&cursor[dst[e]], 1);
        ssrc[p] = src[e];
    }
}

// ---------------- weight prep: transposed, zero-padded, bf16 ----------------
// W1t[208][128] <- W1[100][200]^T ; W2t[112][256] <- W2[200][100]^T

__global__ void prep_weights(const float* __restrict__ W1, const float* __restrict__ W2,
                             ushort_t* __restrict__ W1t, ushort_t* __restrict__ W2t) {
    int i = blockIdx.x * 256 + threadIdx.x;
    if (i < 208 * 128) {
        int n = i >> 7, k = i & 127;
        float v = (n < HDIM && k < CDIM) ? W1[k * HDIM + n] : 0.f;
        W1t[i] = (ushort_t)f2bf(v);
    } else {
        int j = i - 208 * 128;
        if (j < 112 * 256) {
            int n = j >> 8, k = j & 255;
            float v = (n < ODIM && k < HDIM) ? W2[k * ODIM + n] : 0.f;
            W2t[j] = (ushort_t)f2bf(v);
        }
    }
}

// ---------------- embedding gather -> bf16 rows ----------------

__global__ void gather_emb_bf16(const float4* __restrict__ emb, const int* __restrict__ ids,
                                uint2* __restrict__ h0) {
    int i = blockIdx.x * 256 + threadIdx.x;
    const int TOT = N_NODES * (CDIM / 4);  // 1.25M float4s
    if (i < TOT) {
        int n = i / 25, q = i - n * 25;
        float4 v = emb[(size_t)ids[n] * 25 + q];
        uint2 o;
        o.x = f2bf(v.x) | (f2bf(v.y) << 16);
        o.y = f2bf(v.z) | (f2bf(v.w) << 16);
        h0[i] = o;
    }
}

// ---------------- CSR aggregation over bf16 rows (dim 100), fp32 accum ----------
// !BIAS_RELU: write packed bf16 (GEMM input). BIAS_RELU: +bias, relu, write fp32.

template <bool BIAS_RELU>
__global__ __launch_bounds__(256) void agg_bf16(const unsigned* __restrict__ hb,
                                                const int* __restrict__ ssrc,
                                                const int* __restrict__ off,
                                                const float* __restrict__ bias,
                                                unsigned* __restrict__ outb,
                                                float2* __restrict__ outf) {
    int wave = threadIdx.x >> 6;
    int lane = threadIdx.x & 63;
    int n = blockIdx.x * 4 + wave;
    if (n >= N_NODES) return;
    int s0 = off[n], s1 = off[n + 1];
    if (lane >= 50) return;

    float2 a0 = {0.f, 0.f}, a1 = {0.f, 0.f}, a2 = {0.f, 0.f}, a3 = {0.f, 0.f};
    int j = s0;
    for (; j + 3 < s1; j += 4) {
        int r0 = ssrc[j], r1 = ssrc[j + 1], r2 = ssrc[j + 2], r3 = ssrc[j + 3];
        unsigned u0 = hb[(size_t)r0 * 50 + lane];
        unsigned u1 = hb[(size_t)r1 * 50 + lane];
        unsigned u2 = hb[(size_t)r2 * 50 + lane];
        unsigned u3 = hb[(size_t)r3 * 50 + lane];
        a0.x += bflo(u0); a0.y += bfhi(u0);
        a1.x += bflo(u1); a1.y += bfhi(u1);
        a2.x += bflo(u2); a2.y += bfhi(u2);
        a3.x += bflo(u3); a3.y += bfhi(u3);
    }
    {
        int rem = s1 - j;
        if (rem > 0) { unsigned u = hb[(size_t)ssrc[j] * 50 + lane];     a0.x += bflo(u); a0.y += bfhi(u); }
        if (rem > 1) { unsigned u = hb[(size_t)ssrc[j + 1] * 50 + lane]; a1.x += bflo(u); a1.y += bfhi(u); }
        if (rem > 2) { unsigned u = hb[(size_t)ssrc[j + 2] * 50 + lane]; a2.x += bflo(u); a2.y += bfhi(u); }
    }
    float rx = (a0.x + a1.x) + (a2.x + a3.x);
    float ry = (a0.y + a1.y) + (a2.y + a3.y);
    if (BIAS_RELU) {
        rx = fmaxf(rx + bias[2 * lane], 0.f);
        ry = fmaxf(ry + bias[2 * lane + 1], 0.f);
        outf[(size_t)n * 50 + lane] = make_float2(rx, ry);
    } else {
        outb[(size_t)n * 50 + lane] = f2bf(rx) | (f2bf(ry) << 16);
    }
}

// ---------------- MFMA GEMM: out[M,NCOL] = A[M,Kg] @ Wt^T (+bias,relu), bf16 in/out ----
// KE: zero-padded K (mult of 64). A rows are KG_U uints (bf16 pairs) in global.
// Wt: [16*NT][KE] bf16, transposed+padded weights. Block: 4 waves x 16 rows = 64 rows.
// Wave w: rows w*16..+15, all NT 16-col tiles, K-loop in strips of 64.

template <int KE, int KG_U, int NCOL, int NT, bool BIAS_RELU>
__global__ __launch_bounds__(256) void gemm_mfma(const unsigned* __restrict__ A4,
                                                 const ushort_t* __restrict__ Wt,
                                                 const float* __restrict__ bias,
                                                 ushort_t* __restrict__ outb) {
    const int KP = KE + 8;    // As row stride (bf16): +8 keeps 16B align, breaks pow2 banks
    const int KPU = KP / 2;
    const int KEU = KE / 2;
    const int NSTRIP = KE / 64;
    const int WTP = 72;       // WtS row stride (bf16)
    __shared__ ushort_t As[64 * KP];
    __shared__ ushort_t WtS[16 * NT * WTP];
    int tid = threadIdx.x, lane = tid & 63, w = tid >> 6;
    int row0 = blockIdx.x * 64;

    // stage A (64 rows x KE bf16, zero-padded)
    unsigned* AsU = (unsigned*)As;
    for (int idx = tid; idx < 64 * KEU; idx += 256) {
        int r = idx / KEU, kk = idx - r * KEU;
        int row = row0 + r;
        unsigned v = 0;
        if (row < N_NODES && kk < KG_U) v = A4[(size_t)row * KG_U + kk];
        AsU[r * KPU + kk] = v;
    }

    f32x4 acc[NT];
#pragma unroll
    for (int t = 0; t < NT; ++t) acc[t] = (f32x4){0.f, 0.f, 0.f, 0.f};

    const unsigned* WtU = (const unsigned*)Wt;
    unsigned* WtSU = (unsigned*)WtS;
    for (int s = 0; s < NSTRIP; ++s) {
        __syncthreads();  // prev strip consumed (and As visible on s=0... also needed)
        for (int idx = tid; idx < 16 * NT * 32; idx += 256) {
            int n = idx >> 5, kk = idx & 31;
            WtSU[n * (WTP / 2) + kk] = WtU[(size_t)n * KEU + s * 32 + kk];
        }
        __syncthreads();
#pragma unroll
        for (int k2 = 0; k2 < 2; ++k2) {
            int kabs = s * 64 + k2 * 32 + (lane >> 4) * 8;
            bf16x8 a = *reinterpret_cast<const bf16x8*>(&As[(w * 16 + (lane & 15)) * KP + kabs]);
            int kloc = k2 * 32 + (lane >> 4) * 8;
#pragma unroll
            for (int t = 0; t < NT; ++t) {
                bf16x8 b = *reinterpret_cast<const bf16x8*>(&WtS[(t * 16 + (lane & 15)) * WTP + kloc]);
                acc[t] = __builtin_amdgcn_mfma_f32_16x16x32_bf16(a, b, acc[t], 0, 0, 0);
            }
        }
    }

    // epilogue: D layout col=lane&15, row=(lane>>4)*4+i  [m89]
    int col_l = lane & 15, rgrp = lane >> 4;
#pragma unroll
    for (int t = 0; t < NT; ++t) {
        int col = t * 16 + col_l;
        if (col < NCOL) {
            float bv = BIAS_RELU ? bias[col] : 0.f;
#pragma unroll
            for (int i = 0; i < 4; ++i) {
                int row = row0 + w * 16 + rgrp * 4 + i;
                if (row < N_NODES) {
                    float v = acc[t][i];
                    if (BIAS_RELU) v = fmaxf(v + bv, 0.f);
                    outb[(size_t)row * NCOL + col] = (ushort_t)f2bf(v);
                }
            }
        }
    }
}

// ---------------- launch ----------------

extern "C" void kernel_launch(void* const* d_in, const int* in_sizes, int n_in,
                              void* d_out, int out_size, void* d_ws, size_t ws_size,
                              hipStream_t stream) {
    const float* emb = (const float*)d_in[0];
    const float* W1  = (const float*)d_in[1];
    const float* b1  = (const float*)d_in[2];
    const float* W2  = (const float*)d_in[3];
    const float* b2  = (const float*)d_in[4];
    const int* ids   = (const int*)d_in[5];
    const int* esrc  = (const int*)d_in[6];
    const int* edst  = (const int*)d_in[7];
    float* out = (float*)d_out;

    // workspace layout (all 4B-aligned; ~54 MB total)
    ushort_t* h0b = (ushort_t*)d_ws;                    // [N][100] bf16, 10 MB
    ushort_t* a1b = h0b + (size_t)N_NODES * CDIM;       // [N][100] bf16, 10 MB
    ushort_t* h1b = a1b + (size_t)N_NODES * CDIM;       // [N][200] bf16, 20 MB
    ushort_t* gb  = h1b + (size_t)N_NODES * HDIM;       // [N][100] bf16, 10 MB
    ushort_t* W1t = gb + (size_t)N_NODES * ODIM;        // [208][128] bf16
    ushort_t* W2t = W1t + 208 * 128;                    // [112][256] bf16
    int* deg    = (int*)(W2t + 112 * 256);
    int* off    = deg + N_NODES;
    int* cursor = off + (N_NODES + 1);
    int* ssrc   = cursor + N_NODES;                     // 800K ints

    // CSR build (reused by both layers)
    hipMemsetAsync(deg, 0, N_NODES * sizeof(int), stream);
    count_deg<<<(N_EDGES + 255) / 256, 256, 0, stream>>>(edst, deg);
    scan_deg<<<1, 1024, 0, stream>>>(deg, off, cursor);
    scatter_edges<<<(N_EDGES + 255) / 256, 256, 0, stream>>>(esrc, edst, cursor, ssrc);

    // weights -> bf16 transposed padded
    prep_weights<<<(208 * 128 + 112 * 256 + 255) / 256, 256, 0, stream>>>(W1, W2, W1t, W2t);

    // h0 = bf16(emb[ids])
    gather_emb_bf16<<<(N_NODES * 25 + 255) / 256, 256, 0, stream>>>((const float4*)emb, ids,
                                                                    (uint2*)h0b);
    // agg1 = segsum(h0[src])  (bf16 out)
    agg_bf16<false><<<N_NODES / 4, 256, 0, stream>>>((const unsigned*)h0b, ssrc, off,
                                                     nullptr, (unsigned*)a1b, nullptr);
    // h1 = relu(agg1 @ W1 + b1)  (bf16 out)
    gemm_mfma<128, 50, HDIM, 13, true><<<(N_NODES + 63) / 64, 256, 0, stream>>>(
        (const unsigned*)a1b, W1t, b1, h1b);
    // g = h1 @ W2  (bias/relu deferred past linear agg)
    gemm_mfma<256, 100, ODIM, 7, false><<<(N_NODES + 63) / 64, 256, 0, stream>>>(
        (const unsigned*)h1b, W2t, nullptr, gb);
    // out = relu(segsum(g[src]) + b2)  (fp32 out)
    agg_bf16<true><<<N_NODES / 4, 256, 0, stream>>>((const unsigned*)gb, ssrc, off,
                                                    b2, nullptr, (float2*)out);
}